// Round 2
// baseline (370.672 us; speedup 1.0000x reference)
//
#include <hip/hip_runtime.h>
#include <hip/hip_bf16.h>
#include <stdint.h>

// SpatialGraphConv fused: 1x1 conv (192x64) -> graph matmul (K=75) -> BN.
// B=64, C_in=64, T=300, V=25, K=3, C_out=64.  MFMA bf16 16x16x32, fp32 acc.
//
// Round-2 structure:
//  - stage-1 flipped: D = x^T(pixel x ci) @ W^T(ci x o)  -> thread holds 4
//    consecutive pixels (v) per o  -> epilogue is packed ds_write_b64.
//  - pixels padded to 28/t (112 = 7 tiles of 16) so 4-groups never cross t.
//  - stage-2 flipped: D = A^T(w x kv) @ Y(kv x c) -> packed 4-wide stores.
//  - A-operand of stage-2 lives in registers (global/L2 loads), LDS is a
//    48 KB union of xT and Ylds -> 3 blocks/CU.
//  - intermediate is bf16 in d_ws (w padded to 32) when ws_size allows.

#define NBLK 4800  // 64 b * 75 t-tiles

typedef short bf16x8 __attribute__((ext_vector_type(8)));
typedef short short4v __attribute__((ext_vector_type(4)));
typedef float f32x4 __attribute__((ext_vector_type(4)));

struct __attribute__((packed, aligned(4))) F4U { float x, y, z, w; };

static __device__ inline uint32_t pk2(float a, float b) {
    __hip_bfloat162 h = __float22bfloat162_rn(float2{a, b});
    union { __hip_bfloat162 h; uint32_t u; } cv; cv.h = h; return cv.u;
}

template<bool BF16OUT>
__global__ __launch_bounds__(256, 3) void sgc_main(
    const float* __restrict__ x, const float* __restrict__ W,
    const float* __restrict__ bias, const float* __restrict__ A,
    float* __restrict__ outf, uint16_t* __restrict__ yi,
    float* __restrict__ stats_part)
{
    // union: phase A = xT (first 7168 shorts), phase B = Ylds (all 24576)
    __shared__ __align__(16) short buf[24576];  // 48 KB

    const int tid  = threadIdx.x;
    const int lane = tid & 63;
    const int wave = tid >> 6;
    const int bid  = blockIdx.x;
    const int b    = bid / 75;
    const int t0   = (bid % 75) * 4;

    // ---- W fragments (stage-1 B operand: W^T[ci][o]) + bias ----
    bf16x8 wfrag[3][2];
    float bval[3];
    #pragma unroll
    for (int oti = 0; oti < 3; ++oti) {
        int o = (wave * 3 + oti) * 16 + (lane & 15);
        bval[oti] = bias[o];
        #pragma unroll
        for (int kb = 0; kb < 2; ++kb) {
            const float4 f0 = *(const float4*)&W[o * 64 + kb * 32 + (lane >> 4) * 8];
            const float4 f1 = *(const float4*)&W[o * 64 + kb * 32 + (lane >> 4) * 8 + 4];
            union { bf16x8 v; uint32_t u[4]; } p;
            p.u[0] = pk2(f0.x, f0.y); p.u[1] = pk2(f0.z, f0.w);
            p.u[2] = pk2(f1.x, f1.y); p.u[3] = pk2(f1.z, f1.w);
            wfrag[oti][kb] = p.v;
        }
    }

    // ---- stage x -> xT: 400 slots of (8 ci x 2 px), b128 LDS writes ----
    {
        const size_t xbase = (size_t)b * 480000 + (size_t)t0 * 25;
        #pragma unroll
        for (int it = 0; it < 2; ++it) {
            int slot = tid + 256 * it;
            if (slot < 400) {
                int oc = slot / 50;          // ci octet 0..7
                int m  = slot - oc * 50;
                int n  = 2 * m;              // real pixel 0..98
                const float* xp = x + xbase + (size_t)oc * 60000 + n;
                float2 v[8];
                #pragma unroll
                for (int jj = 0; jj < 8; ++jj)
                    v[jj] = *(const float2*)(xp + 7500 * jj);
                union { bf16x8 vv; uint32_t u[4]; } c0, c1;
                #pragma unroll
                for (int q = 0; q < 4; ++q) {
                    c0.u[q] = pk2(v[2*q].x, v[2*q+1].x);
                    c1.u[q] = pk2(v[2*q].y, v[2*q+1].y);
                }
                int kb = oc >> 2, oct = oc & 3;
                int t = n / 25;  int p0 = t * 28 + (n - t * 25);
                int n1 = n + 1;  int t1 = n1 / 25;
                int p1 = t1 * 28 + (n1 - t1 * 25);
                *(bf16x8*)&buf[(((p0 >> 4) * 2 + kb) * 64 + oct * 16 + (p0 & 15)) * 8] = c0.vv;
                *(bf16x8*)&buf[(((p1 >> 4) * 2 + kb) * 64 + oct * 16 + (p1 & 15)) * 8] = c1.vv;
            }
        }
    }
    __syncthreads();

    // ---- stage 1: Y^T(112px x 192o) = x^T @ W^T, per-wave 3 o-tiles ----
    f32x4 acc[3][7];
    #pragma unroll
    for (int oti = 0; oti < 3; ++oti)
        #pragma unroll
        for (int nt = 0; nt < 7; ++nt) {
            f32x4 z = {0.f, 0.f, 0.f, 0.f};
            acc[oti][nt] = z;
        }
    #pragma unroll
    for (int nt = 0; nt < 7; ++nt) {
        bf16x8 xa0 = *(const bf16x8*)&buf[((nt * 2 + 0) * 64 + lane) * 8];
        bf16x8 xa1 = *(const bf16x8*)&buf[((nt * 2 + 1) * 64 + lane) * 8];
        #pragma unroll
        for (int oti = 0; oti < 3; ++oti) {
            acc[oti][nt] = __builtin_amdgcn_mfma_f32_16x16x32_bf16(
                xa0, wfrag[oti][0], acc[oti][nt], 0, 0, 0);
            acc[oti][nt] = __builtin_amdgcn_mfma_f32_16x16x32_bf16(
                xa1, wfrag[oti][1], acc[oti][nt], 0, 0, 0);
        }
    }
    __syncthreads();  // all xT reads done before Ylds overwrites the union

    // ---- stage-2 A operand from global A: A^T[w][kv], kv = k*32+v ----
    bf16x8 bfrag2[2][3];
    #pragma unroll
    for (int mt = 0; mt < 2; ++mt) {
        int w = mt * 16 + (lane & 15);
        #pragma unroll
        for (int kb2 = 0; kb2 < 3; ++kb2) {
            union { bf16x8 vv; uint32_t u[4]; } p;
            #pragma unroll
            for (int q = 0; q < 4; ++q) {
                int v0 = (lane >> 4) * 8 + 2 * q;
                float a0 = (w < 25 && v0     < 25) ? A[(kb2 * 25 + v0    ) * 25 + w] : 0.f;
                float a1 = (w < 25 && v0 + 1 < 25) ? A[(kb2 * 25 + v0 + 1) * 25 + w] : 0.f;
                p.u[q] = pk2(a0, a1);
            }
            bfrag2[mt][kb2] = p.vv;
        }
    }

    // ---- epilogue: acc(+bias) -> Ylds in stage-2 B layout, b64 writes ----
    #pragma unroll
    for (int oti = 0; oti < 3; ++oti) {
        int o = (wave * 3 + oti) * 16 + (lane & 15);
        int k = o >> 6, c = o & 63;
        float bv = bval[oti];
        int cbase = (c >> 4) * 3 + k;
        int cl = c & 15;
        #pragma unroll
        for (int nt = 0; nt < 7; ++nt) {
            int p0 = nt * 16 + (lane >> 4) * 4;
            int t  = p0 / 28;
            int v0 = p0 - t * 28;          // multiple of 4, <= 24
            f32x4 a = acc[oti][nt];
            float e0 = a[0] + bv;
            float e1 = (v0 == 24) ? 0.f : a[1] + bv;
            float e2 = (v0 == 24) ? 0.f : a[2] + bv;
            float e3 = (v0 == 24) ? 0.f : a[3] + bv;
            union { short4v s; uint32_t u[2]; } pk;
            pk.u[0] = pk2(e0, e1); pk.u[1] = pk2(e2, e3);
            int addr = ((t * 12 + cbase) * 64 + (v0 >> 3) * 16 + cl) * 8 + (v0 & 7);
            *(short4v*)&buf[addr] = pk.s;
        }
    }
    // zero the never-written kv=28..31 half-chunks (48*16 slots)
    #pragma unroll
    for (int zz = 0; zz < 3; ++zz) {
        int z = tid + 256 * zz;            // 0..767
        int cl = z & 15, rest = z >> 4;    // rest = (t*4+ct)*3+k, 0..47
        short4v zero4 = {0, 0, 0, 0};
        *(short4v*)&buf[(rest * 64 + 48 + cl) * 8 + 4] = zero4;
    }
    __syncthreads();

    // ---- stage 2: D(w x c) = A^T(w x 96) @ Y(96 x c), per t; wave = c-tile ----
    float ssum = 0.f, ssq = 0.f;
    const int c = wave * 16 + (lane & 15);
    #pragma unroll
    for (int t = 0; t < 4; ++t) {
        bf16x8 yb[3];
        #pragma unroll
        for (int kb2 = 0; kb2 < 3; ++kb2)
            yb[kb2] = *(const bf16x8*)&buf[(((t * 4 + wave) * 3 + kb2) * 64 + lane) * 8];
        #pragma unroll
        for (int mt = 0; mt < 2; ++mt) {
            f32x4 a2 = {0.f, 0.f, 0.f, 0.f};
            #pragma unroll
            for (int kb2 = 0; kb2 < 3; ++kb2)
                a2 = __builtin_amdgcn_mfma_f32_16x16x32_bf16(
                    bfrag2[mt][kb2], yb[kb2], a2, 0, 0, 0);
            int w0 = mt * 16 + (lane >> 4) * 4;
            #pragma unroll
            for (int r = 0; r < 4; ++r)
                if (w0 + r < 25) { ssum += a2[r]; ssq += a2[r] * a2[r]; }
            if (BF16OUT) {
                union { short4v s; uint32_t u[2]; } pk;
                pk.u[0] = pk2(a2[0], a2[1]); pk.u[1] = pk2(a2[2], a2[3]);
                *(short4v*)&yi[(size_t)(b * 300 + t0 + t) * 2048 + c * 32 + w0] = pk.s;
            } else {
                size_t ob = (size_t)(b * 64 + c) * 7500 + (size_t)(t0 + t) * 25 + w0;
                if (w0 < 24) {
                    F4U s = {a2[0], a2[1], a2[2], a2[3]};
                    *(F4U*)&outf[ob] = s;
                } else if (w0 == 24) {
                    outf[ob] = a2[0];
                }
            }
        }
    }
    // stats: lanes l, l+16, l+32, l+48 share c
    ssum += __shfl_xor(ssum, 16); ssum += __shfl_xor(ssum, 32);
    ssq  += __shfl_xor(ssq, 16);  ssq  += __shfl_xor(ssq, 32);
    if (lane < 16) {
        int slot = bid & 63;
        atomicAdd(&stats_part[slot * 128 + c], ssum);
        atomicAdd(&stats_part[slot * 128 + 64 + c], ssq);
    }
}

__global__ void sgc_finalize(const float* __restrict__ stats_part,
                             const float* __restrict__ gamma,
                             const float* __restrict__ beta,
                             float* __restrict__ scaleshift)
{
    int c = threadIdx.x;  // 64 threads
    float s = 0.f, q = 0.f;
    #pragma unroll 8
    for (int slot = 0; slot < 64; ++slot) {
        s += stats_part[slot * 128 + c];
        q += stats_part[slot * 128 + 64 + c];
    }
    const float invN = 1.f / 480000.f;
    float mean = s * invN;
    float var  = q * invN - mean * mean;
    float rstd = rsqrtf(var + 1e-5f);
    float sc = rstd * gamma[c];
    scaleshift[c]      = sc;
    scaleshift[64 + c] = beta[c] - mean * sc;
}

__global__ __launch_bounds__(256) void sgc_norm_bf(
    const uint16_t* __restrict__ yi, const float* __restrict__ ss,
    float* __restrict__ out)
{
    const int nch = 64 * 300 * 2048 / 8;   // 4,915,200 chunks of 8
    int stride = gridDim.x * 256;
    for (int i = blockIdx.x * 256 + threadIdx.x; i < nch; i += stride) {
        int flat = i << 3;
        int w0 = flat & 31;
        int c  = (flat >> 5) & 63;
        int row = (int)((unsigned)flat >> 11);   // b*300 + t
        int b = row / 300, t = row - b * 300;
        float sc = ss[c], sh = ss[64 + c];
        bf16x8 y = *(const bf16x8*)&yi[(size_t)flat];
        float f[8];
        #pragma unroll
        for (int j = 0; j < 8; ++j) {
            union { uint32_t u; float fv; } cv;
            cv.u = ((uint32_t)(uint16_t)y[j]) << 16;
            f[j] = cv.fv * sc + sh;
        }
        size_t ob = (size_t)(b * 64 + c) * 7500 + (size_t)t * 25 + w0;
        if (w0 < 24) {
            F4U s0 = {f[0], f[1], f[2], f[3]};
            F4U s1 = {f[4], f[5], f[6], f[7]};
            *(F4U*)&out[ob] = s0;
            *(F4U*)&out[ob + 4] = s1;
        } else {
            out[ob] = f[0];                 // only w=24 valid in this chunk
        }
    }
}

__global__ __launch_bounds__(256) void sgc_norm_fp(float* __restrict__ out,
                                                   const float* __restrict__ ss)
{
    const int total4 = 30720000 / 4;
    int stride = gridDim.x * 256;
    for (int i = blockIdx.x * 256 + threadIdx.x; i < total4; i += stride) {
        int c = (i / 1875) & 63;
        float sc = ss[c], sh = ss[64 + c];
        float4 v = *((float4*)out + i);
        v.x = v.x * sc + sh;
        v.y = v.y * sc + sh;
        v.z = v.z * sc + sh;
        v.w = v.w * sc + sh;
        *((float4*)out + i) = v;
    }
}

extern "C" void kernel_launch(void* const* d_in, const int* in_sizes, int n_in,
                              void* d_out, int out_size, void* d_ws, size_t ws_size,
                              hipStream_t stream)
{
    const float* x     = (const float*)d_in[0];
    const float* W     = (const float*)d_in[1];
    const float* bias  = (const float*)d_in[2];
    const float* A     = (const float*)d_in[3];
    const float* gamma = (const float*)d_in[4];
    const float* beta  = (const float*)d_in[5];
    float* out = (float*)d_out;

    float* stats      = (float*)d_ws;         // 64 slots * 128 floats = 32 KB
    float* scaleshift = stats + 64 * 128;     // 128 floats
    uint16_t* yi      = (uint16_t*)((char*)d_ws + 40960);
    const size_t need = (size_t)64 * 300 * 2048 * 2 + 40960;  // ~78.7 MB

    hipMemsetAsync(stats, 0, 64 * 128 * sizeof(float), stream);
    if (ws_size >= need) {
        sgc_main<true><<<NBLK, 256, 0, stream>>>(x, W, bias, A, out, yi, stats);
        sgc_finalize<<<1, 64, 0, stream>>>(stats, gamma, beta, scaleshift);
        sgc_norm_bf<<<4096, 256, 0, stream>>>(yi, scaleshift, out);
    } else {
        sgc_main<false><<<NBLK, 256, 0, stream>>>(x, W, bias, A, out, nullptr, stats);
        sgc_finalize<<<1, 64, 0, stream>>>(stats, gamma, beta, scaleshift);
        sgc_norm_fp<<<4096, 256, 0, stream>>>(out, scaleshift);
    }
}